// Round 1
// baseline (154.721 us; speedup 1.0000x reference)
//
#include <hip/hip_runtime.h>

#define N_IMG 8
#define CIN   64
#define H     112
#define W     112
#define P     (H * W)          // 12544
#define D     576              // CIN * 3 * 3
#define COUT  64
#define MEM   1025             // memo table size
#define SENT  P                // sentinel for "no patch yet"

// ---------------------------------------------------------------------------
// 1) per-pixel channel sum: T[n*P + p] = sum_c fmap[n,c,h,w]  (double accum)
__global__ __launch_bounds__(256) void chan_sum_kernel(
    const float* __restrict__ fmap, double* __restrict__ T) {
  int idx = blockIdx.x * blockDim.x + threadIdx.x;   // n*P + p
  if (idx >= N_IMG * P) return;
  int n = idx / P;
  int p = idx - n * P;
  const float* base = fmap + (size_t)n * CIN * P + p;
  double s = 0.0;
  #pragma unroll
  for (int c = 0; c < CIN; ++c) s += (double)base[(size_t)c * P];
  T[idx] = s;
}

// ---------------------------------------------------------------------------
// 2) init first-occurrence table to sentinel
__global__ __launch_bounds__(256) void init_first_kernel(int* __restrict__ first) {
  int i = blockIdx.x * blockDim.x + threadIdx.x;
  if (i < N_IMG * MEM) first[i] = SENT;
}

// ---------------------------------------------------------------------------
// 3) 3x3 zero-padded box sum of T -> quantized bin; atomicMin first[bin]=p
__global__ __launch_bounds__(256) void bins_kernel(
    const double* __restrict__ T, int* __restrict__ bins, int* __restrict__ first) {
  int idx = blockIdx.x * blockDim.x + threadIdx.x;   // n*P + p
  if (idx >= N_IMG * P) return;
  int n = idx / P;
  int p = idx - n * P;
  int h = p / W, w = p - h * W;
  double s = 0.0;
  #pragma unroll
  for (int dh = -1; dh <= 1; ++dh) {
    int hh = h + dh;
    if (hh < 0 || hh >= H) continue;
    #pragma unroll
    for (int dw = -1; dw <= 1; ++dw) {
      int ww = w + dw;
      if (ww < 0 || ww >= W) continue;
      s += T[n * P + hh * W + ww];
    }
  }
  // replicate reference f32 elementwise ops: mean = sum/576 ; v = mean*100 ; trunc
  float sf = (float)s;
  float mean = sf / 576.0f;
  float v = mean * 100.0f;
  int q = (int)v;                       // trunc toward zero == numpy astype(int32)
  int b = q + 512;                      // - MIN_SUMMARY
  b = b < 0 ? 0 : (b > MEM - 1 ? MEM - 1 : b);
  bins[idx] = b;
  atomicMin(&first[n * MEM + b], p);    // device-scope: XCD-safe
}

// ---------------------------------------------------------------------------
// 4) weight transpose: wT[d*COUT + co] = weight[co*D + d]
__global__ __launch_bounds__(256) void wt_kernel(
    const float* __restrict__ weight, float* __restrict__ wT) {
  int i = blockIdx.x * blockDim.x + threadIdx.x;
  if (i >= D * COUT) return;
  int d = i / COUT, co = i - d * COUT;
  wT[i] = weight[co * D + d];
}

// ---------------------------------------------------------------------------
// 5) representative GEMM: one block per (bin, image); skip unused bins.
//    rep[n][b][co] = bias[co] + sum_d patch[d] * wT[d][co]
__global__ __launch_bounds__(256) void rep_kernel(
    const float* __restrict__ fmap, const float* __restrict__ wT,
    const float* __restrict__ bias, const int* __restrict__ first,
    float* __restrict__ rep) {
  int b = blockIdx.x;
  int n = blockIdx.y;
  int fi = first[n * MEM + b];
  if (fi >= SENT) return;               // uniform across block
  __shared__ float patch[D];
  __shared__ float partial[4][COUT];
  int t = threadIdx.x;
  int h = fi / W, w = fi - h * W;
  // gather patch: d = c*9 + kh*3 + kw (conv_general_dilated_patches order)
  for (int d = t; d < D; d += 256) {
    int c = d / 9, r = d - c * 9;
    int kh = r / 3, kw = r - kh * 3;
    int hh = h + kh - 1, ww = w + kw - 1;
    float val = 0.0f;
    if (hh >= 0 && hh < H && ww >= 0 && ww < W)
      val = fmap[((size_t)(n * CIN + c)) * P + hh * W + ww];
    patch[d] = val;
  }
  __syncthreads();
  int co = t & 63, seg = t >> 6;        // 4 segments x 144 d-values
  float acc = 0.0f;
  int d0 = seg * 144;
  #pragma unroll 4
  for (int d = d0; d < d0 + 144; ++d)
    acc += patch[d] * wT[d * COUT + co];
  partial[seg][co] = acc;
  __syncthreads();
  if (t < COUT) {
    float total = partial[0][t] + partial[1][t] + partial[2][t] + partial[3][t] + bias[t];
    rep[((size_t)n * MEM + b) * COUT + t] = total;
  }
}

// ---------------------------------------------------------------------------
// 6) scatter: out[n,co,p] = rep[n, bins[n,p], co], float4 writes
__global__ __launch_bounds__(256) void scatter_kernel(
    const int* __restrict__ bins, const float* __restrict__ rep,
    float* __restrict__ out) {
  int idx = blockIdx.x * blockDim.x + threadIdx.x;   // over N*COUT*(P/4)
  const int PV = P / 4;                               // 3136
  if (idx >= N_IMG * COUT * PV) return;
  int pv = idx % PV;
  int rest = idx / PV;
  int co = rest & 63;
  int n = rest >> 6;
  int4 b4 = *reinterpret_cast<const int4*>(bins + n * P + pv * 4);
  const float* repn = rep + (size_t)n * MEM * COUT + co;
  float4 o;
  o.x = repn[(size_t)b4.x * COUT];
  o.y = repn[(size_t)b4.y * COUT];
  o.z = repn[(size_t)b4.z * COUT];
  o.w = repn[(size_t)b4.w * COUT];
  *reinterpret_cast<float4*>(out + ((size_t)n * COUT + co) * P + pv * 4) = o;
}

// ---------------------------------------------------------------------------
extern "C" void kernel_launch(void* const* d_in, const int* in_sizes, int n_in,
                              void* d_out, int out_size, void* d_ws, size_t ws_size,
                              hipStream_t stream) {
  const float* fmap   = (const float*)d_in[0];
  const float* weight = (const float*)d_in[1];
  const float* bias   = (const float*)d_in[2];
  float* out = (float*)d_out;

  char* ws = (char*)d_ws;
  // workspace layout (all 64B-aligned)
  double* T   = (double*)(ws);                 // 8*12544*8    = 802816 B
  int*   bins = (int*)  (ws + 802816);         // 8*12544*4    = 401408 B
  int*  first = (int*)  (ws + 1204224);        // 8*1025*4     =  32800 B
  float*   wT = (float*)(ws + 1237248);        // 576*64*4     = 147456 B
  float*  rep = (float*)(ws + 1384704);        // 8*1025*64*4  = 2099200 B

  const int NP = N_IMG * P;                    // 100352
  hipLaunchKernelGGL(chan_sum_kernel, dim3((NP + 255) / 256), dim3(256), 0, stream,
                     fmap, T);
  hipLaunchKernelGGL(init_first_kernel, dim3((N_IMG * MEM + 255) / 256), dim3(256), 0, stream,
                     first);
  hipLaunchKernelGGL(bins_kernel, dim3((NP + 255) / 256), dim3(256), 0, stream,
                     T, bins, first);
  hipLaunchKernelGGL(wt_kernel, dim3((D * COUT + 255) / 256), dim3(256), 0, stream,
                     weight, wT);
  hipLaunchKernelGGL(rep_kernel, dim3(MEM, N_IMG), dim3(256), 0, stream,
                     fmap, wT, bias, first, rep);
  hipLaunchKernelGGL(scatter_kernel, dim3((N_IMG * COUT * (P / 4) + 255) / 256), dim3(256), 0, stream,
                     bins, rep, out);
}

// Round 2
// 113.323 us; speedup vs baseline: 1.3653x; 1.3653x over previous
//
#include <hip/hip_runtime.h>

#define N_IMG 8
#define CIN   64
#define H     112
#define W     112
#define P     (H * W)          // 12544
#define PG    (P / 4)          // 3136 float4 pixel-groups
#define D     576              // CIN * 3 * 3
#define COUT  64
#define MEM   1025             // memo table size
#define SENT  P                // sentinel for "no patch yet"

// ---------------------------------------------------------------------------
// 0) prep: init first-table to sentinel + transpose weight
__global__ __launch_bounds__(256) void prep_kernel(
    const float* __restrict__ weight, float* __restrict__ wT,
    int* __restrict__ first) {
  int i = blockIdx.x * 256 + threadIdx.x;
  if (i < N_IMG * MEM) first[i] = SENT;
  if (i < D * COUT) {
    int d = i / COUT, co = i - d * COUT;
    wT[i] = weight[co * D + d];
  }
}

// ---------------------------------------------------------------------------
// 1) per-pixel channel sum, float4-vectorized, channel loop split 4-ways.
//    grid (49, 8): block = 256 threads = 4 channel-quarters x 64 pixel-groups.
__global__ __launch_bounds__(256) void chan_sum_kernel(
    const float* __restrict__ fmap, double* __restrict__ T) {
  __shared__ double partial[4][64][4];
  int t = threadIdx.x;
  int q = t >> 6, lane = t & 63;
  int n = blockIdx.y;
  int pg = blockIdx.x * 64 + lane;         // < 3136 always (49*64 = 3136)
  int p4 = pg * 4;
  const float* base = fmap + (size_t)n * CIN * P + p4;
  double s0 = 0.0, s1 = 0.0, s2 = 0.0, s3 = 0.0;
  int c0 = q * 16;
  #pragma unroll
  for (int c = c0; c < c0 + 16; ++c) {
    float4 v = *reinterpret_cast<const float4*>(base + (size_t)c * P);
    s0 += (double)v.x; s1 += (double)v.y; s2 += (double)v.z; s3 += (double)v.w;
  }
  partial[q][lane][0] = s0; partial[q][lane][1] = s1;
  partial[q][lane][2] = s2; partial[q][lane][3] = s3;
  __syncthreads();
  if (t < 64) {
    double4 o;
    o.x = partial[0][t][0] + partial[1][t][0] + partial[2][t][0] + partial[3][t][0];
    o.y = partial[0][t][1] + partial[1][t][1] + partial[2][t][1] + partial[3][t][1];
    o.z = partial[0][t][2] + partial[1][t][2] + partial[2][t][2] + partial[3][t][2];
    o.w = partial[0][t][3] + partial[1][t][3] + partial[2][t][3] + partial[3][t][3];
    *reinterpret_cast<double4*>(T + (size_t)n * P + (blockIdx.x * 64 + t) * 4) = o;
  }
}

// ---------------------------------------------------------------------------
// 2) 3x3 zero-padded box sum of T -> quantized bin.
//    Per-block LDS first-table, then sparse flush with global atomicMin.
//    grid (13, 8): 1024 threads, one image per block (no n-mixing in LDS table).
__global__ __launch_bounds__(1024) void bins_kernel(
    const double* __restrict__ T, int* __restrict__ bins, int* __restrict__ first) {
  __shared__ int lfirst[MEM];
  int t = threadIdx.x;
  for (int i = t; i < MEM; i += 1024) lfirst[i] = SENT;
  __syncthreads();
  int n = blockIdx.y;
  int p = blockIdx.x * 1024 + t;
  if (p < P) {
    int h = p / W, w = p - h * W;
    const double* Tn = T + (size_t)n * P;
    double s = 0.0;
    #pragma unroll
    for (int dh = -1; dh <= 1; ++dh) {
      int hh = h + dh;
      if (hh < 0 || hh >= H) continue;
      #pragma unroll
      for (int dw = -1; dw <= 1; ++dw) {
        int ww = w + dw;
        if (ww < 0 || ww >= W) continue;
        s += Tn[hh * W + ww];
      }
    }
    // replicate reference f32 elementwise ops: mean = sum/576 ; v = mean*100 ; trunc
    float sf = (float)s;
    float mean = sf / 576.0f;
    float v = mean * 100.0f;
    int qv = (int)v;                    // trunc toward zero == astype(int32)
    int b = qv + 512;                   // - MIN_SUMMARY
    b = b < 0 ? 0 : (b > MEM - 1 ? MEM - 1 : b);
    bins[n * P + p] = b;
    atomicMin(&lfirst[b], p);           // LDS-scope: fast
  }
  __syncthreads();
  for (int i = t; i < MEM; i += 1024) {
    int v = lfirst[i];
    if (v != SENT) atomicMin(&first[n * MEM + i], v);   // ~20-40 per block
  }
}

// ---------------------------------------------------------------------------
// 3) representative GEMM: one block per (bin, image); skip unused bins.
__global__ __launch_bounds__(256) void rep_kernel(
    const float* __restrict__ fmap, const float* __restrict__ wT,
    const float* __restrict__ bias, const int* __restrict__ first,
    float* __restrict__ rep) {
  int b = blockIdx.x;
  int n = blockIdx.y;
  int fi = first[n * MEM + b];
  if (fi >= SENT) return;               // uniform across block
  __shared__ float patch[D];
  __shared__ float partial[4][COUT];
  int t = threadIdx.x;
  int h = fi / W, w = fi - h * W;
  // gather patch: d = c*9 + kh*3 + kw (conv_general_dilated_patches order)
  for (int d = t; d < D; d += 256) {
    int c = d / 9, r = d - c * 9;
    int kh = r / 3, kw = r - kh * 3;
    int hh = h + kh - 1, ww = w + kw - 1;
    float val = 0.0f;
    if (hh >= 0 && hh < H && ww >= 0 && ww < W)
      val = fmap[((size_t)(n * CIN + c)) * P + hh * W + ww];
    patch[d] = val;
  }
  __syncthreads();
  int co = t & 63, seg = t >> 6;        // 4 segments x 144 d-values
  float acc = 0.0f;
  int d0 = seg * 144;
  #pragma unroll 4
  for (int d = d0; d < d0 + 144; ++d)
    acc += patch[d] * wT[d * COUT + co];
  partial[seg][co] = acc;
  __syncthreads();
  if (t < COUT) {
    float total = partial[0][t] + partial[1][t] + partial[2][t] + partial[3][t] + bias[t];
    rep[((size_t)n * MEM + b) * COUT + t] = total;
  }
}

// ---------------------------------------------------------------------------
// 4) scatter: out[n,co,p] = rep[n, bins[n,p], co], float4 writes
__global__ __launch_bounds__(256) void scatter_kernel(
    const int* __restrict__ bins, const float* __restrict__ rep,
    float* __restrict__ out) {
  int idx = blockIdx.x * blockDim.x + threadIdx.x;   // over N*COUT*(P/4)
  const int PV = P / 4;                               // 3136
  if (idx >= N_IMG * COUT * PV) return;
  int pv = idx % PV;
  int rest = idx / PV;
  int co = rest & 63;
  int n = rest >> 6;
  int4 b4 = *reinterpret_cast<const int4*>(bins + n * P + pv * 4);
  const float* repn = rep + (size_t)n * MEM * COUT + co;
  float4 o;
  o.x = repn[(size_t)b4.x * COUT];
  o.y = repn[(size_t)b4.y * COUT];
  o.z = repn[(size_t)b4.z * COUT];
  o.w = repn[(size_t)b4.w * COUT];
  *reinterpret_cast<float4*>(out + ((size_t)n * COUT + co) * P + pv * 4) = o;
}

// ---------------------------------------------------------------------------
extern "C" void kernel_launch(void* const* d_in, const int* in_sizes, int n_in,
                              void* d_out, int out_size, void* d_ws, size_t ws_size,
                              hipStream_t stream) {
  const float* fmap   = (const float*)d_in[0];
  const float* weight = (const float*)d_in[1];
  const float* bias   = (const float*)d_in[2];
  float* out = (float*)d_out;

  char* ws = (char*)d_ws;
  // workspace layout (all 64B-aligned)
  double* T   = (double*)(ws);                 // 8*12544*8    = 802816 B
  int*   bins = (int*)  (ws + 802816);         // 8*12544*4    = 401408 B
  int*  first = (int*)  (ws + 1204224);        // 8*1025*4     =  32800 B
  float*   wT = (float*)(ws + 1237248);        // 576*64*4     = 147456 B
  float*  rep = (float*)(ws + 1384704);        // 8*1025*64*4  = 2099200 B

  hipLaunchKernelGGL(prep_kernel, dim3(144), dim3(256), 0, stream,
                     weight, wT, first);
  hipLaunchKernelGGL(chan_sum_kernel, dim3(49, 8), dim3(256), 0, stream,
                     fmap, T);
  hipLaunchKernelGGL(bins_kernel, dim3(13, 8), dim3(1024), 0, stream,
                     T, bins, first);
  hipLaunchKernelGGL(rep_kernel, dim3(MEM, N_IMG), dim3(256), 0, stream,
                     fmap, wT, bias, first, rep);
  hipLaunchKernelGGL(scatter_kernel, dim3((N_IMG * COUT * (P / 4) + 255) / 256), dim3(256), 0, stream,
                     bins, rep, out);
}